// Round 1
// baseline (1956.496 us; speedup 1.0000x reference)
//
#include <hip/hip_runtime.h>

// Problem constants (match reference setup_inputs)
constexpr int NUM_NODES = 1000000;
constexpr int D_IN  = 128;
constexpr int D_OUT = 128;
constexpr int R1    = 17;            // NUM_REL + 1
constexpr int BATCH = 16384;
constexpr int S     = 32;            // NUM_SAMPLE
constexpr int K     = R1 * D_IN;     // 2176

constexpr int NODES_PER_BLOCK = 8;
constexpr int THREADS = 256;

__global__ __launch_bounds__(THREADS, 2)
void rgcn_fused_f32(const float* __restrict__ embed,   // [NUM_NODES, 128]
                    const float* __restrict__ W,       // [17, 128, 128] (r, o, i)
                    const int*   __restrict__ nbrs,    // [BATCH, 32]
                    const int*   __restrict__ rels,    // [BATCH, 32]
                    float* __restrict__ out)           // [BATCH, 128]
{
    __shared__ float agg[NODES_PER_BLOCK][K];   // 8*2176*4 = 69632 B

    const int t = threadIdx.x;
    const int node0 = blockIdx.x * NODES_PER_BLOCK;

    // ---- zero agg ----
    float* aggf = &agg[0][0];
    for (int idx = t; idx < NODES_PER_BLOCK * K; idx += THREADS)
        aggf[idx] = 0.0f;
    __syncthreads();

    // ---- phase 1: gather neighbor embeddings, accumulate per-relation sums ----
    // half-block (128 threads = 2 waves) owns one node at a time; each wave owns
    // a disjoint (node, d-range) so agg RMW has no cross-wave races.
    {
        const int half = t >> 7;        // 0 or 1
        const int d    = t & 127;
        for (int p = 0; p < NODES_PER_BLOCK / 2; ++p) {
            const int nl = p * 2 + half;
            const int gn = node0 + nl;
            const int* __restrict__ nb = nbrs + gn * S;
            const int* __restrict__ rl = rels + gn * S;
            #pragma unroll 4
            for (int s = 0; s < S; ++s) {
                const int idx = nb[s];            // wave-uniform -> scalar load
                const int r   = rl[s];            // wave-uniform
                const float v = embed[(size_t)idx * D_IN + d];
                agg[nl][r * D_IN + d] += v;       // LDS RMW, thread-owned addr
            }
        }
    }
    __syncthreads();

    // ---- phase 2: out[n][o] = sum_{r,i} agg[n][r*128+i] * W[r][o][i] ----
    // thread -> (node = t>>5, 4 consecutive outputs o0..o0+3)
    {
        const int nl = t >> 5;                    // 0..7
        const int gn = node0 + nl;
        const int o0 = (t & 31) * 4;              // 0..124

        float acc0 = 0.f, acc1 = 0.f, acc2 = 0.f, acc3 = 0.f;

        for (int r = 0; r < R1; ++r) {
            const float* __restrict__ wr = W + (size_t)r * D_OUT * D_IN;
            const float* __restrict__ ar = &agg[nl][r * D_IN];
            #pragma unroll 4
            for (int i = 0; i < D_IN; i += 4) {
                const float4 a4 = *reinterpret_cast<const float4*>(ar + i);
                const float4 w0 = *reinterpret_cast<const float4*>(wr + (o0 + 0) * D_IN + i);
                const float4 w1 = *reinterpret_cast<const float4*>(wr + (o0 + 1) * D_IN + i);
                const float4 w2 = *reinterpret_cast<const float4*>(wr + (o0 + 2) * D_IN + i);
                const float4 w3 = *reinterpret_cast<const float4*>(wr + (o0 + 3) * D_IN + i);
                acc0 += a4.x * w0.x + a4.y * w0.y + a4.z * w0.z + a4.w * w0.w;
                acc1 += a4.x * w1.x + a4.y * w1.y + a4.z * w1.z + a4.w * w1.w;
                acc2 += a4.x * w2.x + a4.y * w2.y + a4.z * w2.z + a4.w * w2.w;
                acc3 += a4.x * w3.x + a4.y * w3.y + a4.z * w3.z + a4.w * w3.w;
            }
        }

        // reference: (sum/32 per relation) -> matmul -> /17 -> *1000 -> relu
        const float sc = 1000.0f / (float)(S * R1);
        float4 res;
        res.x = fmaxf(acc0 * sc, 0.0f);
        res.y = fmaxf(acc1 * sc, 0.0f);
        res.z = fmaxf(acc2 * sc, 0.0f);
        res.w = fmaxf(acc3 * sc, 0.0f);
        *reinterpret_cast<float4*>(out + (size_t)gn * D_OUT + o0) = res;
    }
}

extern "C" void kernel_launch(void* const* d_in, const int* in_sizes, int n_in,
                              void* d_out, int out_size, void* d_ws, size_t ws_size,
                              hipStream_t stream) {
    const float* embed = (const float*)d_in[0];
    const float* W     = (const float*)d_in[1];
    const int*   nbrs  = (const int*)d_in[2];
    const int*   rels  = (const int*)d_in[3];
    float* out = (float*)d_out;

    const int grid = BATCH / NODES_PER_BLOCK;   // 2048
    hipLaunchKernelGGL(rgcn_fused_f32, dim3(grid), dim3(THREADS), 0, stream,
                       embed, W, nbrs, rels, out);
}

// Round 2
// 156.355 us; speedup vs baseline: 12.5131x; 12.5131x over previous
//
#include <hip/hip_runtime.h>

// Problem constants (match reference setup_inputs)
constexpr int D     = 128;            // D_IN == D_OUT
constexpr int R1    = 17;             // NUM_REL + 1
constexpr int BATCH = 16384;
constexpr int S     = 32;             // NUM_SAMPLE
constexpr int K     = R1 * D;         // 2176 (GEMM K dim)
constexpr int KB    = K / 8;          // 272 k-blocks of 8
constexpr int NPB   = 16;             // nodes (M rows) per block
constexpr int AGG_STRIDE = K + 4;     // 2180 dwords; pad so LDS rows land on different banks
constexpr int THREADS = 1024;

typedef __attribute__((ext_vector_type(8))) short short8;  // bf16x8 MFMA fragment
typedef __attribute__((ext_vector_type(4))) float f32x4;   // MFMA accumulator

__device__ __forceinline__ short f2bf(float f) {
    // round-to-nearest-even f32 -> bf16 (finite inputs)
    union { float f; unsigned u; } c; c.f = f;
    unsigned u = c.u;
    u += 0x7fffu + ((u >> 16) & 1u);
    return (short)(u >> 16);
}

// Pack W[17][128][128] (r,o,i) f32 -> Bp bf16 in B-fragment order:
// Bp[ot][kb][o][j]  where o_global = ot*16+o, k = kb*8+j, k = r*128+i.
// A wave's per-step fragment load is then 64 lanes x 16B fully contiguous (1 KB).
__global__ void pack_w_kernel(const float* __restrict__ W, short* __restrict__ Bp) {
    int tid = blockIdx.x * 256 + threadIdx.x;
    if (tid >= R1 * D * D) return;
    int og = tid / K;            // 0..127 (output col)
    int k  = tid - og * K;       // 0..2175
    int r = k >> 7, i = k & 127;
    float v = W[((size_t)r * D + og) * D + i];
    int ot = og >> 4, o = og & 15, kb = k >> 3, j = k & 7;
    Bp[(((size_t)ot * KB + kb) * 16 + o) * 8 + j] = f2bf(v);
}

__global__ __launch_bounds__(THREADS, 4)
void rgcn_kernel(const float* __restrict__ embed,   // [1e6][128] f32
                 const short* __restrict__ Bp,      // packed bf16 weights (d_ws)
                 const int*   __restrict__ nbrs,    // [16384][32]
                 const int*   __restrict__ rels,    // [16384][32]
                 float* __restrict__ out)           // [16384][128]
{
    __shared__ float agg[NPB][AGG_STRIDE];          // 139,520 B

    const int t     = threadIdx.x;
    const int lane  = t & 63;
    const int node0 = blockIdx.x * NPB;

    // ---------------- phase 1: gather + per-relation accumulate (registers) -------------
    {
        const int d = t & 127;          // embedding dim owned by this thread
        const int g = t >> 7;           // 0..7 -> node group
        #pragma unroll
        for (int p = 0; p < 2; ++p) {
            const int nl = g * 2 + p;
            const int gn = node0 + nl;
            // one coalesced load: lanes 0..31 hold the 32 neighbor ids,
            // lanes 32..63 hold the 32 relation ids
            int my;
            if (lane < 32) my = nbrs[(size_t)gn * S + lane];
            else           my = rels[(size_t)gn * S + (lane - 32)];

            float a0=0,a1=0,a2=0,a3=0,a4=0,a5=0,a6=0,a7=0,a8=0,
                  a9=0,a10=0,a11=0,a12=0,a13=0,a14=0,a15=0,a16=0;

            #pragma unroll
            for (int s = 0; s < S; ++s) {
                const int idx = __builtin_amdgcn_readlane(my, s);        // scalar
                const int r   = __builtin_amdgcn_readlane(my, s + 32);   // scalar
                const float v = embed[(size_t)idx * D + d];              // coalesced 256B/wave
                switch (r) {   // wave-uniform -> scalar branch cascade, 1 VALU add/sample
                    case 0:  a0  += v; break;  case 1:  a1  += v; break;
                    case 2:  a2  += v; break;  case 3:  a3  += v; break;
                    case 4:  a4  += v; break;  case 5:  a5  += v; break;
                    case 6:  a6  += v; break;  case 7:  a7  += v; break;
                    case 8:  a8  += v; break;  case 9:  a9  += v; break;
                    case 10: a10 += v; break;  case 11: a11 += v; break;
                    case 12: a12 += v; break;  case 13: a13 += v; break;
                    case 14: a14 += v; break;  case 15: a15 += v; break;
                    default: a16 += v; break;
                }
            }
            float* arow = &agg[nl][d];
            arow[0*D]=a0;   arow[1*D]=a1;   arow[2*D]=a2;   arow[3*D]=a3;
            arow[4*D]=a4;   arow[5*D]=a5;   arow[6*D]=a6;   arow[7*D]=a7;
            arow[8*D]=a8;   arow[9*D]=a9;   arow[10*D]=a10; arow[11*D]=a11;
            arow[12*D]=a12; arow[13*D]=a13; arow[14*D]=a14; arow[15*D]=a15;
            arow[16*D]=a16;
        }
    }
    __syncthreads();

    // ---------------- phase 2: C[16 x 128] = A[16 x 2176] @ B via bf16 MFMA -------------
    // waves 0..3 each compute a 16x32 output slab; waves 4..15 retire.
    const int w = t >> 6;
    if (w < 4) {
        const int m   = lane & 15;      // node row (A) / output col-in-tile (B)
        const int kb4 = lane >> 4;      // k-subblock 0..3

        f32x4 acc0 = {0.f,0.f,0.f,0.f};
        f32x4 acc1 = {0.f,0.f,0.f,0.f};

        const float* ap    = &agg[m][kb4 * 8];
        const short* bbase = Bp + (((size_t)(w * 2) * KB + kb4) * 16 + m) * 8;
        constexpr int BHALF = KB * 16 * 8;   // 34816 elems between 16-col tiles

        #pragma unroll 4
        for (int step = 0; step < K / 32; ++step) {
            const float4 x = *reinterpret_cast<const float4*>(ap + step * 32);
            const float4 y = *reinterpret_cast<const float4*>(ap + step * 32 + 4);
            short8 af;
            af[0]=f2bf(x.x); af[1]=f2bf(x.y); af[2]=f2bf(x.z); af[3]=f2bf(x.w);
            af[4]=f2bf(y.x); af[5]=f2bf(y.y); af[6]=f2bf(y.z); af[7]=f2bf(y.w);
            const short8 b0 = *reinterpret_cast<const short8*>(bbase + (size_t)step * 512);
            const short8 b1 = *reinterpret_cast<const short8*>(bbase + BHALF + (size_t)step * 512);
            acc0 = __builtin_amdgcn_mfma_f32_16x16x32_bf16(af, b0, acc0, 0, 0, 0);
            acc1 = __builtin_amdgcn_mfma_f32_16x16x32_bf16(af, b1, acc1, 0, 0, 0);
        }

        const float sc = 1000.0f / (float)(S * R1);
        float* op = out + (size_t)node0 * D + w * 32;
        #pragma unroll
        for (int j = 0; j < 4; ++j) {
            const int node = kb4 * 4 + j;            // C/D: row = (lane>>4)*4 + reg
            float* orow = op + (size_t)node * D;
            orow[m]      = fmaxf(acc0[j] * sc, 0.0f);
            orow[16 + m] = fmaxf(acc1[j] * sc, 0.0f);
        }
    }
}

extern "C" void kernel_launch(void* const* d_in, const int* in_sizes, int n_in,
                              void* d_out, int out_size, void* d_ws, size_t ws_size,
                              hipStream_t stream) {
    const float* embed = (const float*)d_in[0];
    const float* W     = (const float*)d_in[1];
    const int*   nbrs  = (const int*)d_in[2];
    const int*   rels  = (const int*)d_in[3];
    float* out = (float*)d_out;
    short* Bp  = (short*)d_ws;   // 17*128*128*2 B = 557,056 B of scratch

    hipLaunchKernelGGL(pack_w_kernel, dim3((R1 * D * D + 255) / 256), dim3(256), 0, stream,
                       W, Bp);
    hipLaunchKernelGGL(rgcn_kernel, dim3(BATCH / NPB), dim3(THREADS), 0, stream,
                       embed, Bp, nbrs, rels, out);
}

// Round 3
// 101.416 us; speedup vs baseline: 19.2917x; 1.5417x over previous
//
#include <hip/hip_runtime.h>

// Problem constants (match reference setup_inputs)
constexpr int D     = 128;            // D_IN == D_OUT
constexpr int R1    = 17;             // NUM_REL + 1
constexpr int BATCH = 16384;
constexpr int S     = 32;             // NUM_SAMPLE
constexpr int K     = R1 * D;         // 2176 (GEMM K dim)
constexpr int KB    = K / 8;          // 272 k-blocks of 8
constexpr int NPB   = 16;             // nodes (M rows) per block
constexpr int AS    = K + 8;          // agg16 row stride in shorts (4368 B: 16B-aligned, bank-offset 4)
constexpr int THREADS = 512;

typedef __attribute__((ext_vector_type(8))) short short8;  // bf16x8 MFMA fragment
typedef __attribute__((ext_vector_type(4))) float f32x4;   // MFMA accumulator

__device__ __forceinline__ short f2bf(float f) {
    // round-to-nearest-even f32 -> bf16 (finite inputs)
    union { float f; unsigned u; } c; c.f = f;
    unsigned u = c.u;
    u += 0x7fffu + ((u >> 16) & 1u);
    return (short)(u >> 16);
}

// Pack W[17][128][128] (r,o,i) f32 -> Bp bf16 in B-fragment order:
// Bp[ot][kb][o][j]  where o_global = ot*16+o, k = kb*8+j, k = r*128+i.
// A wave's per-step fragment load is then 64 lanes x 16B fully contiguous (1 KB).
__global__ void pack_w_kernel(const float* __restrict__ W, short* __restrict__ Bp) {
    int tid = blockIdx.x * 256 + threadIdx.x;
    if (tid >= R1 * D * D) return;
    int og = tid / K;            // 0..127 (output col)
    int k  = tid - og * K;       // 0..2175
    int r = k >> 7, i = k & 127;
    float v = W[((size_t)r * D + og) * D + i];
    int ot = og >> 4, o = og & 15, kb = k >> 3, j = k & 7;
    Bp[(((size_t)ot * KB + kb) * 16 + o) * 8 + j] = f2bf(v);
}

__global__ __launch_bounds__(THREADS, 4)   // 4 waves/EU -> 2 blocks/CU, VGPR cap 128
void rgcn_kernel(const float* __restrict__ embed,   // [1e6][128] f32
                 const short* __restrict__ Bp,      // packed bf16 weights (d_ws)
                 const int*   __restrict__ nbrs,    // [16384][32]
                 const int*   __restrict__ rels,    // [16384][32]
                 float* __restrict__ out)           // [16384][128]
{
    __shared__ short agg16[NPB][AS];                // 16*2184*2 = 69,888 B -> 2 blocks/CU

    const int t     = threadIdx.x;
    const int lane  = t & 63;
    const int node0 = blockIdx.x * NPB;

    // ---------------- phase 1: gather + per-relation accumulate (registers) -------------
    // thread -> embedding dim d; group g (128 threads) handles 4 nodes serially.
    {
        const int d = t & 127;
        const int g = t >> 7;           // 0..3
        #pragma unroll
        for (int p = 0; p < 4; ++p) {
            const int nl = g * 4 + p;
            const int gn = node0 + nl;
            // one coalesced load: lanes 0..31 hold the 32 neighbor ids,
            // lanes 32..63 hold the 32 relation ids
            int my;
            if (lane < 32) my = nbrs[(size_t)gn * S + lane];
            else           my = rels[(size_t)gn * S + (lane - 32)];

            // ---- batch ALL 32 gather loads first (no branches in between) ----
            float v[S];                 // fully unrolled, compile-time indices -> registers
            #pragma unroll
            for (int s = 0; s < S; ++s) {
                const int idx = __builtin_amdgcn_readlane(my, s);      // scalar
                v[s] = embed[(size_t)idx * D + d];                     // coalesced 256B/wave
            }

            // ---- then the branchy accumulate (loads already in flight/landed) ----
            float a0=0,a1=0,a2=0,a3=0,a4=0,a5=0,a6=0,a7=0,a8=0,
                  a9=0,a10=0,a11=0,a12=0,a13=0,a14=0,a15=0,a16=0;
            #pragma unroll
            for (int s = 0; s < S; ++s) {
                const int r = __builtin_amdgcn_readlane(my, s + 32);   // scalar
                const float x = v[s];
                switch (r) {
                    case 0:  a0  += x; break;  case 1:  a1  += x; break;
                    case 2:  a2  += x; break;  case 3:  a3  += x; break;
                    case 4:  a4  += x; break;  case 5:  a5  += x; break;
                    case 6:  a6  += x; break;  case 7:  a7  += x; break;
                    case 8:  a8  += x; break;  case 9:  a9  += x; break;
                    case 10: a10 += x; break;  case 11: a11 += x; break;
                    case 12: a12 += x; break;  case 13: a13 += x; break;
                    case 14: a14 += x; break;  case 15: a15 += x; break;
                    default: a16 += x; break;
                }
            }

            short* arow = &agg16[nl][d];
            arow[0*D]=f2bf(a0);   arow[1*D]=f2bf(a1);   arow[2*D]=f2bf(a2);
            arow[3*D]=f2bf(a3);   arow[4*D]=f2bf(a4);   arow[5*D]=f2bf(a5);
            arow[6*D]=f2bf(a6);   arow[7*D]=f2bf(a7);   arow[8*D]=f2bf(a8);
            arow[9*D]=f2bf(a9);   arow[10*D]=f2bf(a10); arow[11*D]=f2bf(a11);
            arow[12*D]=f2bf(a12); arow[13*D]=f2bf(a13); arow[14*D]=f2bf(a14);
            arow[15*D]=f2bf(a15); arow[16*D]=f2bf(a16);
        }
    }
    __syncthreads();

    // ---------------- phase 2: C[16 x 128] = A[16 x 2176] @ B via bf16 MFMA -------------
    // all 8 waves active; wave w computes output cols [w*16, w*16+16).
    {
        const int w   = t >> 6;
        const int m   = lane & 15;      // node row (A) / output col-in-tile (B)
        const int kb4 = lane >> 4;      // k-subblock 0..3

        f32x4 acc = {0.f, 0.f, 0.f, 0.f};

        const short* ar = &agg16[m][kb4 * 8];
        const short* bb = Bp + (((size_t)w * KB + kb4) * 16 + m) * 8;

        #pragma unroll 4
        for (int step = 0; step < K / 32; ++step) {
            const short8 a = *reinterpret_cast<const short8*>(ar + step * 32);
            const short8 b = *reinterpret_cast<const short8*>(bb + (size_t)step * 512);
            acc = __builtin_amdgcn_mfma_f32_16x16x32_bf16(a, b, acc, 0, 0, 0);
        }

        const float sc = 1000.0f / (float)(S * R1);
        #pragma unroll
        for (int j = 0; j < 4; ++j) {
            const int node = kb4 * 4 + j;            // C/D: row = (lane>>4)*4 + reg
            out[(size_t)(node0 + node) * D + w * 16 + m] = fmaxf(acc[j] * sc, 0.0f);
        }
    }
}

extern "C" void kernel_launch(void* const* d_in, const int* in_sizes, int n_in,
                              void* d_out, int out_size, void* d_ws, size_t ws_size,
                              hipStream_t stream) {
    const float* embed = (const float*)d_in[0];
    const float* W     = (const float*)d_in[1];
    const int*   nbrs  = (const int*)d_in[2];
    const int*   rels  = (const int*)d_in[3];
    float* out = (float*)d_out;
    short* Bp  = (short*)d_ws;   // 17*128*128*2 B = 557,056 B of scratch

    hipLaunchKernelGGL(pack_w_kernel, dim3((R1 * D * D + 255) / 256), dim3(256), 0, stream,
                       W, Bp);
    hipLaunchKernelGGL(rgcn_kernel, dim3(BATCH / NPB), dim3(THREADS), 0, stream,
                       embed, Bp, nbrs, rels, out);
}

// Round 4
// 80.523 us; speedup vs baseline: 24.2972x; 1.2595x over previous
//
#include <hip/hip_runtime.h>

// Problem constants (match reference setup_inputs)
constexpr int D     = 128;            // D_IN == D_OUT
constexpr int R1    = 17;             // NUM_REL + 1
constexpr int BATCH = 16384;
constexpr int S     = 32;             // NUM_SAMPLE
constexpr int K     = R1 * D;         // 2176 (GEMM K dim)
constexpr int KB    = K / 8;          // 272 k-blocks of 8
constexpr int NPB   = 16;             // nodes (M rows) per block
constexpr int AS    = K + 8;          // agg16 row stride in shorts (4368 B)
constexpr int THREADS = 512;

typedef __attribute__((ext_vector_type(8))) short short8;  // bf16x8 MFMA fragment
typedef __attribute__((ext_vector_type(4))) float f32x4;   // MFMA accumulator

__device__ __forceinline__ unsigned short f2bf_u(float f) {
    union { float f; unsigned u; } c; c.f = f;
    unsigned u = c.u;
    u += 0x7fffu + ((u >> 16) & 1u);
    return (unsigned short)(u >> 16);
}

__device__ __forceinline__ unsigned pack2bf(float lo, float hi) {
    return (unsigned)f2bf_u(lo) | ((unsigned)f2bf_u(hi) << 16);
}

// Pack W[17][128][128] (r,o,i) f32 -> Bp bf16 in B-fragment order:
// Bp[ot][kb][o][j]  where o_global = ot*16+o, k = kb*8+j, k = r*128+i.
__global__ void pack_w_kernel(const float* __restrict__ W, short* __restrict__ Bp) {
    int tid = blockIdx.x * 256 + threadIdx.x;
    if (tid >= R1 * D * D) return;
    int og = tid / K;            // 0..127 (output col)
    int k  = tid - og * K;       // 0..2175
    int r = k >> 7, i = k & 127;
    float v = W[((size_t)r * D + og) * D + i];
    int ot = og >> 4, o = og & 15, kb = k >> 3, j = k & 7;
    Bp[(((size_t)ot * KB + kb) * 16 + o) * 8 + j] = (short)f2bf_u(v);
}

// accumulate helper: wave-uniform relation r -> scalar branch, adds x into a[r]
#define ACC_SWITCH(r, x)                                              \
    switch (r) {                                                      \
        case 0:  a0.x  += x.x; a0.y  += x.y; break;                   \
        case 1:  a1.x  += x.x; a1.y  += x.y; break;                   \
        case 2:  a2.x  += x.x; a2.y  += x.y; break;                   \
        case 3:  a3.x  += x.x; a3.y  += x.y; break;                   \
        case 4:  a4.x  += x.x; a4.y  += x.y; break;                   \
        case 5:  a5.x  += x.x; a5.y  += x.y; break;                   \
        case 6:  a6.x  += x.x; a6.y  += x.y; break;                   \
        case 7:  a7.x  += x.x; a7.y  += x.y; break;                   \
        case 8:  a8.x  += x.x; a8.y  += x.y; break;                   \
        case 9:  a9.x  += x.x; a9.y  += x.y; break;                   \
        case 10: a10.x += x.x; a10.y += x.y; break;                   \
        case 11: a11.x += x.x; a11.y += x.y; break;                   \
        case 12: a12.x += x.x; a12.y += x.y; break;                   \
        case 13: a13.x += x.x; a13.y += x.y; break;                   \
        case 14: a14.x += x.x; a14.y += x.y; break;                   \
        case 15: a15.x += x.x; a15.y += x.y; break;                   \
        default: a16.x += x.x; a16.y += x.y; break;                   \
    }

__global__ __launch_bounds__(THREADS, 4)   // 4 waves/EU -> 2 blocks/CU, VGPR cap 128
void rgcn_kernel(const float* __restrict__ embed,   // [1e6][128] f32
                 const short* __restrict__ Bp,      // packed bf16 weights (d_ws)
                 const int*   __restrict__ nbrs,    // [16384][32]
                 const int*   __restrict__ rels,    // [16384][32]
                 float* __restrict__ out)           // [16384][128]
{
    __shared__ short agg16[NPB][AS];                // 16*2184*2 = 69,888 B -> 2 blocks/CU

    const int t     = threadIdx.x;
    const int lane  = t & 63;
    const int w     = t >> 6;                        // wave 0..7
    const int node0 = blockIdx.x * NPB;

    // ---------------- phase 1: gather + per-relation accumulate -------------
    // wave w handles nodes w*2, w*2+1. Each lane owns dims {2*lane, 2*lane+1}
    // -> one full 512B embed row per wave-load (perfectly coalesced float2).
    #pragma unroll 1
    for (int p = 0; p < 2; ++p) {
        const int nl = w * 2 + p;
        const int gn = node0 + nl;
        // one coalesced load: lanes 0..31 = neighbor ids, lanes 32..63 = relation ids
        int my;
        if (lane < 32) my = nbrs[(size_t)gn * S + lane];
        else           my = rels[(size_t)gn * S + (lane - 32)];

        float2 a0={0,0},a1={0,0},a2={0,0},a3={0,0},a4={0,0},a5={0,0},
               a6={0,0},a7={0,0},a8={0,0},a9={0,0},a10={0,0},a11={0,0},
               a12={0,0},a13={0,0},a14={0,0},a15={0,0},a16={0,0};

        // two chunks of 16 samples: batch the 16 gather loads (SGPR-base
        // addressing via readlane idx), then the branchy accumulate.
        #pragma unroll 1
        for (int c = 0; c < 2; ++c) {
            const int sbase = c * 16;
            float2 v[16];
            #pragma unroll
            for (int j = 0; j < 16; ++j) {
                const int idx = __builtin_amdgcn_readlane(my, sbase + j);   // SGPR
                v[j] = *reinterpret_cast<const float2*>(embed + (size_t)idx * D + 2 * lane);
            }
            #pragma unroll
            for (int j = 0; j < 16; ++j) {
                const int r = __builtin_amdgcn_readlane(my, 32 + sbase + j); // SGPR
                const float2 x = v[j];
                ACC_SWITCH(r, x)
            }
        }

        // packed bf16x2 LDS stores: dword index = r*64 + lane (conflict-free)
        unsigned* arow = reinterpret_cast<unsigned*>(&agg16[nl][2 * lane]);
        arow[0*64]  = pack2bf(a0.x,  a0.y);   arow[1*64]  = pack2bf(a1.x,  a1.y);
        arow[2*64]  = pack2bf(a2.x,  a2.y);   arow[3*64]  = pack2bf(a3.x,  a3.y);
        arow[4*64]  = pack2bf(a4.x,  a4.y);   arow[5*64]  = pack2bf(a5.x,  a5.y);
        arow[6*64]  = pack2bf(a6.x,  a6.y);   arow[7*64]  = pack2bf(a7.x,  a7.y);
        arow[8*64]  = pack2bf(a8.x,  a8.y);   arow[9*64]  = pack2bf(a9.x,  a9.y);
        arow[10*64] = pack2bf(a10.x, a10.y);  arow[11*64] = pack2bf(a11.x, a11.y);
        arow[12*64] = pack2bf(a12.x, a12.y);  arow[13*64] = pack2bf(a13.x, a13.y);
        arow[14*64] = pack2bf(a14.x, a14.y);  arow[15*64] = pack2bf(a15.x, a15.y);
        arow[16*64] = pack2bf(a16.x, a16.y);
    }
    __syncthreads();

    // ---------------- phase 2: C[16 x 128] = A[16 x 2176] @ B via bf16 MFMA -------------
    // wave w computes output cols [w*16, w*16+16).
    {
        const int m   = lane & 15;      // node row (A) / output col-in-tile (B)
        const int kb4 = lane >> 4;      // k-subblock 0..3

        f32x4 acc = {0.f, 0.f, 0.f, 0.f};

        const short* ar = &agg16[m][kb4 * 8];
        const short* bb = Bp + (((size_t)w * KB + kb4) * 16 + m) * 8;

        #pragma unroll 4
        for (int step = 0; step < K / 32; ++step) {
            const short8 a = *reinterpret_cast<const short8*>(ar + step * 32);
            const short8 b = *reinterpret_cast<const short8*>(bb + (size_t)step * 512);
            acc = __builtin_amdgcn_mfma_f32_16x16x32_bf16(a, b, acc, 0, 0, 0);
        }

        const float sc = 1000.0f / (float)(S * R1);
        #pragma unroll
        for (int j = 0; j < 4; ++j) {
            const int node = kb4 * 4 + j;            // C/D: row = (lane>>4)*4 + reg
            out[(size_t)(node0 + node) * D + w * 16 + m] = fmaxf(acc[j] * sc, 0.0f);
        }
    }
}

extern "C" void kernel_launch(void* const* d_in, const int* in_sizes, int n_in,
                              void* d_out, int out_size, void* d_ws, size_t ws_size,
                              hipStream_t stream) {
    const float* embed = (const float*)d_in[0];
    const float* W     = (const float*)d_in[1];
    const int*   nbrs  = (const int*)d_in[2];
    const int*   rels  = (const int*)d_in[3];
    float* out = (float*)d_out;
    short* Bp  = (short*)d_ws;   // 17*128*128*2 B = 557,056 B of scratch

    hipLaunchKernelGGL(pack_w_kernel, dim3((R1 * D * D + 255) / 256), dim3(256), 0, stream,
                       W, Bp);
    hipLaunchKernelGGL(rgcn_kernel, dim3(BATCH / NPB), dim3(THREADS), 0, stream,
                       embed, Bp, nbrs, rels, out);
}